// Round 1
// baseline (295.368 us; speedup 1.0000x reference)
//
#include <hip/hip_runtime.h>

// EnergyFunction: B=2, S=2048, D=1024, H=8, hd=128
//   K = x@Wk^T, V = x@Wv^T, Sf = x@Wself^T   (all bf16 intermediates)
//   att = softmax(-(K K^T)/sqrt(128), causal) @ V
//   out = (att + Sf) @ Wout^T                 (fp32 output)
// ws layout (40 MB): xb/Tb 0..8M | Wkb 8M | Wvb 10M | Wsb 12M | Wob 14M
//                    | Kb 16M | Vtb 24M (pre-transposed [BH][128][2048]) | Sbf 32M

typedef unsigned short u16;
typedef short s16x8 __attribute__((ext_vector_type(8)));
typedef short s16x4 __attribute__((ext_vector_type(4)));
typedef unsigned short u16x4 __attribute__((ext_vector_type(4)));
typedef float f32x4 __attribute__((ext_vector_type(4)));

#define DEV __device__ __forceinline__

DEV u16 f2bf(float f) {
    union { float f; unsigned u; } v; v.f = f;
    return (u16)((v.u + 0x7FFFu + ((v.u >> 16) & 1u)) >> 16);
}
DEV float bf2f(u16 h) {
    union { unsigned u; float f; } v; v.u = ((unsigned)h) << 16;
    return v.f;
}
DEV void gload16(const void* g, void* l) {
    __builtin_amdgcn_global_load_lds(
        (const __attribute__((address_space(1))) void*)g,
        (__attribute__((address_space(3))) void*)l, 16, 0, 0);
}

// ---------------- cast fp32 -> bf16 (x + 4 weights fused) ----------------
__global__ __launch_bounds__(256) void cast_all(
    const float* __restrict__ x, const float* __restrict__ wk,
    const float* __restrict__ wv, const float* __restrict__ wsf,
    const float* __restrict__ wo,
    u16* __restrict__ xb, u16* __restrict__ wkb, u16* __restrict__ wvb,
    u16* __restrict__ wsb, u16* __restrict__ wob) {
    int i = blockIdx.x * 256 + threadIdx.x;            // float4 index
    const int NX = (2 * 2048 * 1024) / 4;              // 1048576
    const int NW = (1024 * 1024) / 4;                  // 262144
    const float* src; u16* dst; int off;
    if (i < NX)              { src = x;   dst = xb;  off = i; }
    else if (i < NX + NW)    { src = wk;  dst = wkb; off = i - NX; }
    else if (i < NX + 2*NW)  { src = wv;  dst = wvb; off = i - NX - NW; }
    else if (i < NX + 3*NW)  { src = wsf; dst = wsb; off = i - NX - 2*NW; }
    else                     { src = wo;  dst = wob; off = i - NX - 3*NW; }
    float4 v = ((const float4*)src)[off];
    u16x4 o = { f2bf(v.x), f2bf(v.y), f2bf(v.z), f2bf(v.w) };
    ((u16x4*)dst)[off] = o;
}

// ---------------- NT GEMM: C[m][n] = sum_k A[m][k]*W[n][k] ----------------
// 128x128 tile, BK=32, 4 waves (2x2), 16x16x32 bf16 MFMA, global_load_lds.
// MODE 0: z picks {Wk->Kb (bf16), Wv->Vtb (bf16, per-head transposed), Wself->Sbf}
// MODE 1: bf16 in -> fp32 out (final projection)
template <int MODE>
__global__ __launch_bounds__(256) void gemm_nt(
    const u16* __restrict__ A, const u16* __restrict__ W0,
    const u16* __restrict__ W1, const u16* __restrict__ W2,
    u16* __restrict__ O0, u16* __restrict__ O1, u16* __restrict__ O2,
    float* __restrict__ Of) {
    __shared__ u16 As[128 * 32];
    __shared__ u16 Bs[128 * 32];
    const int tid = threadIdx.x, lane = tid & 63, wave = tid >> 6;
    const int wr = wave >> 1, wc = wave & 1;
    const int m0 = blockIdx.y * 128, n0 = blockIdx.x * 128;
    const u16* Bw = W0;
    if (MODE == 0) Bw = (blockIdx.z == 0) ? W0 : (blockIdx.z == 1) ? W1 : W2;

    f32x4 acc[4][4];
#pragma unroll
    for (int i = 0; i < 4; ++i)
#pragma unroll
        for (int j = 0; j < 4; ++j) acc[i][j] = f32x4{0.f, 0.f, 0.f, 0.f};

    // staging geometry: tile [128 rows][32 k] bf16, rows of 64B
    const int o1 = wave * 1024 + lane * 16;
    const int r1 = o1 >> 6, c1 = (o1 & 63) >> 1;
    const int o2 = o1 + 4096;
    const int r2 = o2 >> 6, c2 = (o2 & 63) >> 1;

    for (int k0 = 0; k0 < 1024; k0 += 32) {
        gload16(A  + ((size_t)(m0 + r1) << 10) + k0 + c1, (char*)As + wave * 1024);
        gload16(A  + ((size_t)(m0 + r2) << 10) + k0 + c2, (char*)As + 4096 + wave * 1024);
        gload16(Bw + ((size_t)(n0 + r1) << 10) + k0 + c1, (char*)Bs + wave * 1024);
        gload16(Bw + ((size_t)(n0 + r2) << 10) + k0 + c2, (char*)Bs + 4096 + wave * 1024);
        __syncthreads();
        const int kb = (lane >> 4) << 3;
        s16x8 af[4], bfr[4];
#pragma unroll
        for (int i = 0; i < 4; ++i) {
            af[i]  = *(const s16x8*)&As[(wr * 64 + i * 16 + (lane & 15)) * 32 + kb];
            bfr[i] = *(const s16x8*)&Bs[(wc * 64 + i * 16 + (lane & 15)) * 32 + kb];
        }
#pragma unroll
        for (int i = 0; i < 4; ++i)
#pragma unroll
            for (int j = 0; j < 4; ++j)
                acc[i][j] = __builtin_amdgcn_mfma_f32_16x16x32_bf16(af[i], bfr[j], acc[i][j], 0, 0, 0);
        __syncthreads();
    }

    // epilogue: C/D layout col=lane&15 (n), row=(lane>>4)*4+reg (m)
    const int mb0 = m0 + wr * 64, nb0 = n0 + wc * 64;
    if (MODE == 1) {
#pragma unroll
        for (int i = 0; i < 4; ++i)
#pragma unroll
            for (int j = 0; j < 4; ++j) {
                int n = nb0 + j * 16 + (lane & 15);
                int mbase = mb0 + i * 16 + ((lane >> 4) << 2);
#pragma unroll
                for (int r = 0; r < 4; ++r)
                    Of[((size_t)(mbase + r) << 10) + n] = acc[i][j][r];
            }
    } else if (blockIdx.z == 1) {
        // V: write transposed per head: Vt[(b*8+h)*128 + d][s], pack 4 s per store
#pragma unroll
        for (int i = 0; i < 4; ++i)
#pragma unroll
            for (int j = 0; j < 4; ++j) {
                int n = nb0 + j * 16 + (lane & 15);
                int h = n >> 7, d = n & 127;
                int mbase = mb0 + i * 16 + ((lane >> 4) << 2);
                int b = mbase >> 11, s = mbase & 2047;
                u16x4 pk;
#pragma unroll
                for (int r = 0; r < 4; ++r) pk[r] = f2bf(acc[i][j][r]);
                *(u16x4*)(O1 + (((size_t)(b * 8 + h) << 7) + d) * 2048 + s) = pk;
            }
    } else {
        u16* dst = blockIdx.z ? O2 : O0;
#pragma unroll
        for (int i = 0; i < 4; ++i)
#pragma unroll
            for (int j = 0; j < 4; ++j) {
                int n = nb0 + j * 16 + (lane & 15);
                int mbase = mb0 + i * 16 + ((lane >> 4) << 2);
#pragma unroll
                for (int r = 0; r < 4; ++r)
                    dst[((size_t)(mbase + r) << 10) + n] = f2bf(acc[i][j][r]);
            }
    }
}

// ---------------- causal flash attention over keys ----------------
// grid (32 qtiles, 16 bh), 256 thr. Wave w owns q rows qt*64+w*16..+15.
// Swapped QK^T: mfma(A=K-frag [m=attn_k], B=Q-frag [n=q]) -> lane holds a
// P-column (q = lane&15, k spread over hi-groups/regs). Softmax reduce =
// 2x shfl_xor. P repacked in-register as PV's A-operand with the same
// k-bijection used to read V^T fragments (dot products are k-permutation
// invariant as long as both operands agree).
__global__ __launch_bounds__(256) void attn_kernel(
    const u16* __restrict__ Kb, const u16* __restrict__ Vtb,
    const u16* __restrict__ Sb, u16* __restrict__ Tb) {
    __shared__ u16 Ks[64 * 128];   // K tile [k][dhead], XOR-swizzled rows
    __shared__ u16 Vs[128 * 64];   // V^T tile [dhead][k], XOR-swizzled rows
    const int tid = threadIdx.x, lane = tid & 63, wave = tid >> 6;
    const int qt = 31 - blockIdx.x;          // big q-tiles first (load balance)
    const int bh = blockIdx.y, b = bh >> 3, h = bh & 7;
    const int hi = lane >> 4, lo = lane & 15;
    const int qlocal = wave * 16 + lo;
    const int qrow = qt * 64 + qlocal;

    s16x8 qf[4];
    {
        const u16* qp = Kb + ((size_t)(b * 2048 + qrow) << 10) + h * 128 + (hi << 3);
#pragma unroll
        for (int c = 0; c < 4; ++c) qf[c] = *(const s16x8*)(qp + c * 32);
    }
    f32x4 oacc[8];
#pragma unroll
    for (int nf = 0; nf < 8; ++nf) oacc[nf] = f32x4{0.f, 0.f, 0.f, 0.f};
    float mrun = -__builtin_inff(), lrun = 0.f;
    const float SC = -0.12751741566723328f;  // -log2(e)/sqrt(128)

    for (int kt = 0; kt <= qt; ++kt) {
        const int ks0 = kt << 6;
        __syncthreads();  // previous tile's LDS reads done before overwrite
#pragma unroll
        for (int j = 0; j < 4; ++j) {
            int o = tid * 16 + j * 4096;
            {   // K tile: 64 rows x 256B
                int r = o >> 8, cb = o & 255;
                s16x8 v = *(const s16x8*)(Kb + ((size_t)(b * 2048 + ks0 + r) << 10) + h * 128 + (cb >> 1));
                *(s16x8*)((char*)Ks + r * 256 + (cb ^ ((r & 7) << 4))) = v;
            }
            {   // Vt tile: 128 rows x 128B
                int d = o >> 7, kb2 = o & 127;
                s16x8 v = *(const s16x8*)(Vtb + (((size_t)(bh * 128 + d)) << 11) + ks0 + (kb2 >> 1));
                *(s16x8*)((char*)Vs + d * 128 + (kb2 ^ ((d & 7) << 4))) = v;
            }
        }
        __syncthreads();

        // QK^T (swapped): sf[mf] reg r = score[k = ks0+mf*16+hi*4+r][q]
        f32x4 sf[4];
#pragma unroll
        for (int mf = 0; mf < 4; ++mf) {
            f32x4 s = {0.f, 0.f, 0.f, 0.f};
            int kr = mf * 16 + lo;
            const char* rowp = (const char*)Ks + kr * 256;
            int swz = (kr & 7) << 4;
#pragma unroll
            for (int c = 0; c < 4; ++c) {
                s16x8 kf = *(const s16x8*)(rowp + ((c * 64 + hi * 16) ^ swz));
                s = __builtin_amdgcn_mfma_f32_16x16x32_bf16(kf, qf[c], s, 0, 0, 0);
            }
            sf[mf] = s;
        }

        const bool diag = (kt == qt);
        float p[4][4];
        float pm = -__builtin_inff();
#pragma unroll
        for (int mf = 0; mf < 4; ++mf)
#pragma unroll
            for (int r = 0; r < 4; ++r) {
                float sv = sf[mf][r] * SC;
                if (diag) {
                    int klocal = mf * 16 + (hi << 2) + r;
                    if (klocal > qlocal) sv = -__builtin_inff();
                }
                p[mf][r] = sv;
                pm = fmaxf(pm, sv);
            }
        pm = fmaxf(pm, __shfl_xor(pm, 16));
        pm = fmaxf(pm, __shfl_xor(pm, 32));
        float mnew = fmaxf(mrun, pm);
        float corr = exp2f(mrun - mnew);     // first tile: exp2(-inf)=0
        float psum = 0.f;
#pragma unroll
        for (int mf = 0; mf < 4; ++mf)
#pragma unroll
            for (int r = 0; r < 4; ++r) {
                float e = exp2f(p[mf][r] - mnew);
                p[mf][r] = e;
                psum += e;
            }
        psum += __shfl_xor(psum, 16);
        psum += __shfl_xor(psum, 32);
        lrun = lrun * corr + psum;
        mrun = mnew;

        // rescale output acc (acc rows hold q = hi*4+r -> broadcast corr)
        float cr[4];
#pragma unroll
        for (int r = 0; r < 4; ++r) cr[r] = __shfl(corr, (hi << 2) + r);
#pragma unroll
        for (int nf = 0; nf < 8; ++nf)
#pragma unroll
            for (int r = 0; r < 4; ++r) oacc[nf][r] *= cr[r];

        // pack P (bf16) as PV A-operand; k-bijection: slot i of chunk c2
        //   -> k = 32*c2 + hi*4 + (i&3) + 16*(i>>2)
        s16x8 pa[2];
#pragma unroll
        for (int c2 = 0; c2 < 2; ++c2) {
            s16x8 t;
#pragma unroll
            for (int e = 0; e < 4; ++e) t[e] = (short)f2bf(p[2 * c2][e]);
#pragma unroll
            for (int e = 0; e < 4; ++e) t[4 + e] = (short)f2bf(p[2 * c2 + 1][e]);
            pa[c2] = t;
        }
        // PV: B-frag slot i reads Vs[d][same k-bijection]
#pragma unroll
        for (int nf = 0; nf < 8; ++nf) {
            int d = nf * 16 + lo;
            const char* vrow = (const char*)Vs + d * 128;
            int swz = (d & 7) << 4;
#pragma unroll
            for (int c2 = 0; c2 < 2; ++c2) {
                int ob = (hi << 3) + (c2 << 6);
                s16x4 vlo = *(const s16x4*)(vrow + (ob ^ swz));
                s16x4 vhi = *(const s16x4*)(vrow + ((ob + 32) ^ swz));
                s16x8 vf = {vlo[0], vlo[1], vlo[2], vlo[3], vhi[0], vhi[1], vhi[2], vhi[3]};
                oacc[nf] = __builtin_amdgcn_mfma_f32_16x16x32_bf16(pa[c2], vf, oacc[nf], 0, 0, 0);
            }
        }
    }

    // epilogue: normalize, add self-force, write bf16 T
    float linv[4];
#pragma unroll
    for (int r = 0; r < 4; ++r) linv[r] = 1.0f / __shfl(lrun, (hi << 2) + r);
#pragma unroll
    for (int nf = 0; nf < 8; ++nf) {
        int d = nf * 16 + lo;
#pragma unroll
        for (int r = 0; r < 4; ++r) {
            int q2 = qt * 64 + wave * 16 + (hi << 2) + r;
            size_t idx = ((size_t)(b * 2048 + q2) << 10) + h * 128 + d;
            Tb[idx] = f2bf(oacc[nf][r] * linv[r] + bf2f(Sb[idx]));
        }
    }
}

// ---------------- launch ----------------
extern "C" void kernel_launch(void* const* d_in, const int* in_sizes, int n_in,
                              void* d_out, int out_size, void* d_ws, size_t ws_size,
                              hipStream_t stream) {
    const float* x   = (const float*)d_in[0];
    const float* Wk  = (const float*)d_in[1];
    const float* Wv  = (const float*)d_in[2];
    const float* Wsf = (const float*)d_in[3];
    const float* Wo  = (const float*)d_in[4];
    float* out = (float*)d_out;
    char* ws = (char*)d_ws;
    u16* xb  = (u16*)(ws);                       // 8 MB (reused as Tb after proj)
    u16* wkb = (u16*)(ws + (8u << 20));
    u16* wvb = (u16*)(ws + (10u << 20));
    u16* wsb = (u16*)(ws + (12u << 20));
    u16* wob = (u16*)(ws + (14u << 20));
    u16* Kb  = (u16*)(ws + (16u << 20));         // 8 MB
    u16* Vtb = (u16*)(ws + (24u << 20));         // 8 MB, [BH][128][2048]
    u16* Sbf = (u16*)(ws + (32u << 20));         // 8 MB
    u16* Tb  = xb;                               // alias: xb dead after proj GEMM

    cast_all<<<8192, 256, 0, stream>>>(x, Wk, Wv, Wsf, Wo, xb, wkb, wvb, wsb, wob);
    gemm_nt<0><<<dim3(8, 32, 3), 256, 0, stream>>>(xb, wkb, wvb, wsb, Kb, Vtb, Sbf, nullptr);
    attn_kernel<<<dim3(32, 16), 256, 0, stream>>>(Kb, Vtb, Sbf, Tb);
    gemm_nt<1><<<dim3(8, 32, 1), 256, 0, stream>>>(Tb, wob, nullptr, nullptr,
                                                   nullptr, nullptr, nullptr, out);
}

// Round 2
// 242.966 us; speedup vs baseline: 1.2157x; 1.2157x over previous
//
#include <hip/hip_runtime.h>

// EnergyFunction: B=2, S=2048, D=1024, H=8, hd=128
//   K = x@Wk^T, V = x@Wv^T, Sf = x@Wself^T   (all bf16 intermediates)
//   att = softmax(-(K K^T)/sqrt(128), causal) @ V
//   out = (att + Sf) @ Wout^T                 (fp32 output)
// ws layout (40 MB): xb/Tb 0..8M | Wkb 8M | Wvb 10M | Wsb 12M | Wob 14M
//                    | Kb 16M | Vtb 24M (pre-transposed [BH][128][2048]) | Sbf 32M

typedef unsigned short u16;
typedef short s16x8 __attribute__((ext_vector_type(8)));
typedef short s16x4 __attribute__((ext_vector_type(4)));
typedef unsigned short u16x4 __attribute__((ext_vector_type(4)));
typedef float f32x4 __attribute__((ext_vector_type(4)));

#define DEV __device__ __forceinline__

DEV u16 f2bf(float f) {
    union { float f; unsigned u; } v; v.f = f;
    return (u16)((v.u + 0x7FFFu + ((v.u >> 16) & 1u)) >> 16);
}
DEV float bf2f(u16 h) {
    union { unsigned u; float f; } v; v.u = ((unsigned)h) << 16;
    return v.f;
}
DEV void gload16(const void* g, void* l) {
    __builtin_amdgcn_global_load_lds(
        (const __attribute__((address_space(1))) void*)g,
        (__attribute__((address_space(3))) void*)l, 16, 0, 0);
}

#define FULL_BARRIER()                          \
    do {                                        \
        __builtin_amdgcn_sched_barrier(0);      \
        __builtin_amdgcn_s_barrier();           \
        __builtin_amdgcn_sched_barrier(0);      \
    } while (0)

// ---------------- cast fp32 -> bf16 (x + 4 weights fused) ----------------
__global__ __launch_bounds__(256) void cast_all(
    const float* __restrict__ x, const float* __restrict__ wk,
    const float* __restrict__ wv, const float* __restrict__ wsf,
    const float* __restrict__ wo,
    u16* __restrict__ xb, u16* __restrict__ wkb, u16* __restrict__ wvb,
    u16* __restrict__ wsb, u16* __restrict__ wob) {
    int i = blockIdx.x * 256 + threadIdx.x;            // float4 index
    const int NX = (2 * 2048 * 1024) / 4;              // 1048576
    const int NW = (1024 * 1024) / 4;                  // 262144
    const float* src; u16* dst; int off;
    if (i < NX)              { src = x;   dst = xb;  off = i; }
    else if (i < NX + NW)    { src = wk;  dst = wkb; off = i - NX; }
    else if (i < NX + 2*NW)  { src = wv;  dst = wvb; off = i - NX - NW; }
    else if (i < NX + 3*NW)  { src = wsf; dst = wsb; off = i - NX - 2*NW; }
    else                     { src = wo;  dst = wob; off = i - NX - 3*NW; }
    float4 v = ((const float4*)src)[off];
    u16x4 o = { f2bf(v.x), f2bf(v.y), f2bf(v.z), f2bf(v.w) };
    ((u16x4*)dst)[off] = o;
}

// ---------------- NT GEMM: C[m][n] = sum_k A[m][k]*W[n][k] ----------------
// 128x128 tile, BK=32, 4 waves (2x2), 16x16x32 bf16 MFMA, global_load_lds.
// MODE 0: z picks {Wk->Kb (bf16), Wv->Vtb (bf16, per-head transposed), Wself->Sbf}
// MODE 1: bf16 in -> fp32 out (final projection)
template <int MODE>
__global__ __launch_bounds__(256) void gemm_nt(
    const u16* __restrict__ A, const u16* __restrict__ W0,
    const u16* __restrict__ W1, const u16* __restrict__ W2,
    u16* __restrict__ O0, u16* __restrict__ O1, u16* __restrict__ O2,
    float* __restrict__ Of) {
    __shared__ u16 As[128 * 32];
    __shared__ u16 Bs[128 * 32];
    const int tid = threadIdx.x, lane = tid & 63, wave = tid >> 6;
    const int wr = wave >> 1, wc = wave & 1;
    const int m0 = blockIdx.y * 128, n0 = blockIdx.x * 128;
    const u16* Bw = W0;
    if (MODE == 0) Bw = (blockIdx.z == 0) ? W0 : (blockIdx.z == 1) ? W1 : W2;

    f32x4 acc[4][4];
#pragma unroll
    for (int i = 0; i < 4; ++i)
#pragma unroll
        for (int j = 0; j < 4; ++j) acc[i][j] = f32x4{0.f, 0.f, 0.f, 0.f};

    // staging geometry: tile [128 rows][32 k] bf16, rows of 64B
    const int o1 = wave * 1024 + lane * 16;
    const int r1 = o1 >> 6, c1 = (o1 & 63) >> 1;
    const int o2 = o1 + 4096;
    const int r2 = o2 >> 6, c2 = (o2 & 63) >> 1;

    for (int k0 = 0; k0 < 1024; k0 += 32) {
        gload16(A  + ((size_t)(m0 + r1) << 10) + k0 + c1, (char*)As + wave * 1024);
        gload16(A  + ((size_t)(m0 + r2) << 10) + k0 + c2, (char*)As + 4096 + wave * 1024);
        gload16(Bw + ((size_t)(n0 + r1) << 10) + k0 + c1, (char*)Bs + wave * 1024);
        gload16(Bw + ((size_t)(n0 + r2) << 10) + k0 + c2, (char*)Bs + 4096 + wave * 1024);
        __syncthreads();
        const int kb = (lane >> 4) << 3;
        s16x8 af[4], bfr[4];
#pragma unroll
        for (int i = 0; i < 4; ++i) {
            af[i]  = *(const s16x8*)&As[(wr * 64 + i * 16 + (lane & 15)) * 32 + kb];
            bfr[i] = *(const s16x8*)&Bs[(wc * 64 + i * 16 + (lane & 15)) * 32 + kb];
        }
#pragma unroll
        for (int i = 0; i < 4; ++i)
#pragma unroll
            for (int j = 0; j < 4; ++j)
                acc[i][j] = __builtin_amdgcn_mfma_f32_16x16x32_bf16(af[i], bfr[j], acc[i][j], 0, 0, 0);
        __syncthreads();
    }

    // epilogue: C/D layout col=lane&15 (n), row=(lane>>4)*4+reg (m)
    const int mb0 = m0 + wr * 64, nb0 = n0 + wc * 64;
    if (MODE == 1) {
#pragma unroll
        for (int i = 0; i < 4; ++i)
#pragma unroll
            for (int j = 0; j < 4; ++j) {
                int n = nb0 + j * 16 + (lane & 15);
                int mbase = mb0 + i * 16 + ((lane >> 4) << 2);
#pragma unroll
                for (int r = 0; r < 4; ++r)
                    Of[((size_t)(mbase + r) << 10) + n] = acc[i][j][r];
            }
    } else if (blockIdx.z == 1) {
        // V: write transposed per head: Vt[(b*8+h)*128 + d][s], pack 4 s per store
#pragma unroll
        for (int i = 0; i < 4; ++i)
#pragma unroll
            for (int j = 0; j < 4; ++j) {
                int n = nb0 + j * 16 + (lane & 15);
                int h = n >> 7, d = n & 127;
                int mbase = mb0 + i * 16 + ((lane >> 4) << 2);
                int b = mbase >> 11, s = mbase & 2047;
                u16x4 pk;
#pragma unroll
                for (int r = 0; r < 4; ++r) pk[r] = f2bf(acc[i][j][r]);
                *(u16x4*)(O1 + (((size_t)(b * 8 + h) << 7) + d) * 2048 + s) = pk;
            }
    } else {
        u16* dst = blockIdx.z ? O2 : O0;
#pragma unroll
        for (int i = 0; i < 4; ++i)
#pragma unroll
            for (int j = 0; j < 4; ++j) {
                int n = nb0 + j * 16 + (lane & 15);
                int mbase = mb0 + i * 16 + ((lane >> 4) << 2);
#pragma unroll
                for (int r = 0; r < 4; ++r)
                    dst[((size_t)(mbase + r) << 10) + n] = f2bf(acc[i][j][r]);
            }
    }
}

// ---------------- causal flash attention over keys ----------------
// grid (32 qtiles, 16 bh), 256 thr. Wave w owns q rows qt*64+w*16..+15.
// Double-buffered K/V tiles staged via global_load_lds with PRE-SWIZZLED
// per-lane global source (linear LDS dest + swizzled read = rule-21-correct).
// Counted vmcnt(8): next tile's 8 loads stay in flight under compute.
__global__ __launch_bounds__(256) void attn_kernel(
    const u16* __restrict__ Kb, const u16* __restrict__ Vtb,
    const u16* __restrict__ Sb, u16* __restrict__ Tb) {
    __shared__ u16 Ks[2][64 * 128];   // K tile [k][dhead], XOR-swizzled rows
    __shared__ u16 Vs[2][128 * 64];   // V^T tile [dhead][k], XOR-swizzled rows
    const int tid = threadIdx.x, lane = tid & 63, wave = tid >> 6;
    const int qt = 31 - blockIdx.x;          // big q-tiles first (load balance)
    const int bh = blockIdx.y, b = bh >> 3, h = bh & 7;
    const int hi = lane >> 4, lo = lane & 15;
    const int qlocal = wave * 16 + lo;
    const int qrow = qt * 64 + qlocal;

    s16x8 qf[4];
    {
        const u16* qp = Kb + ((size_t)(b * 2048 + qrow) << 10) + h * 128 + (hi << 3);
#pragma unroll
        for (int c = 0; c < 4; ++c) qf[c] = *(const s16x8*)(qp + c * 32);
    }

    // pre-swizzled staging source bases (per-lane), linear LDS dests (per-wave)
    const u16* ksrcb[4];
    const u16* vsrcb[4];
    int ldst[4];
#pragma unroll
    for (int j = 0; j < 4; ++j) {
        int p = wave * 4096 + j * 1024 + lane * 16;   // linear byte pos in 16KB tile
        ldst[j] = wave * 4096 + j * 1024;             // wave-uniform LDS dest
        int rk = p >> 8, cbs = (p & 255) ^ ((rk & 7) << 4);
        ksrcb[j] = Kb + ((size_t)(b * 2048 + rk) << 10) + h * 128 + (cbs >> 1);
        int dv = p >> 7, kbs = (p & 127) ^ ((dv & 7) << 4);
        vsrcb[j] = Vtb + (((size_t)(bh * 128 + dv)) << 11) + (kbs >> 1);
    }

    auto stage = [&](int ks0, int buf) {
        char* kb = (char*)Ks[buf];
        char* vb = (char*)Vs[buf];
#pragma unroll
        for (int j = 0; j < 4; ++j) {
            gload16(ksrcb[j] + ((size_t)ks0 << 10), kb + ldst[j]);
            gload16(vsrcb[j] + ks0, vb + ldst[j]);
        }
    };

    f32x4 oacc[8];
#pragma unroll
    for (int nf = 0; nf < 8; ++nf) oacc[nf] = f32x4{0.f, 0.f, 0.f, 0.f};
    float mrun = -__builtin_inff(), lrun = 0.f;
    const float SC = -0.12751741566723328f;  // -log2(e)/sqrt(128)

    stage(0, 0);
    asm volatile("s_waitcnt vmcnt(0)" ::: "memory");
    FULL_BARRIER();

    for (int kt = 0; kt <= qt; ++kt) {
        const int cur = kt & 1;
        if (kt < qt) {
            stage((kt + 1) << 6, cur ^ 1);            // 8 loads in flight
            asm volatile("s_waitcnt vmcnt(8)" ::: "memory");
        } else {
            asm volatile("s_waitcnt vmcnt(0)" ::: "memory");
        }
        FULL_BARRIER();                               // tile kt landed for all waves

        // QK^T (swapped): sf[mf] reg r = score[k = ks0+mf*16+hi*4+r][q]
        f32x4 sf[4];
        __builtin_amdgcn_s_setprio(1);
#pragma unroll
        for (int mf = 0; mf < 4; ++mf) {
            f32x4 s = {0.f, 0.f, 0.f, 0.f};
            int kr = mf * 16 + lo;
            const char* rowp = (const char*)Ks[cur] + kr * 256;
            int swz = (kr & 7) << 4;
#pragma unroll
            for (int c = 0; c < 4; ++c) {
                s16x8 kf = *(const s16x8*)(rowp + ((c * 64 + hi * 16) ^ swz));
                s = __builtin_amdgcn_mfma_f32_16x16x32_bf16(kf, qf[c], s, 0, 0, 0);
            }
            sf[mf] = s;
        }
        __builtin_amdgcn_s_setprio(0);

        const bool diag = (kt == qt);
        float p[4][4];
        float pm = -__builtin_inff();
#pragma unroll
        for (int mf = 0; mf < 4; ++mf)
#pragma unroll
            for (int r = 0; r < 4; ++r) {
                float sv = sf[mf][r] * SC;
                if (diag) {
                    int klocal = mf * 16 + (hi << 2) + r;
                    if (klocal > qlocal) sv = -__builtin_inff();
                }
                p[mf][r] = sv;
                pm = fmaxf(pm, sv);
            }
        pm = fmaxf(pm, __shfl_xor(pm, 16));
        pm = fmaxf(pm, __shfl_xor(pm, 32));
        float mnew = fmaxf(mrun, pm);
        float corr = exp2f(mrun - mnew);     // first tile: exp2(-inf)=0
        float psum = 0.f;
#pragma unroll
        for (int mf = 0; mf < 4; ++mf)
#pragma unroll
            for (int r = 0; r < 4; ++r) {
                float e = exp2f(p[mf][r] - mnew);
                p[mf][r] = e;
                psum += e;
            }
        psum += __shfl_xor(psum, 16);
        psum += __shfl_xor(psum, 32);
        lrun = lrun * corr + psum;
        mrun = mnew;

        // rescale output acc (acc rows hold q = hi*4+r -> broadcast corr)
        float cr[4];
#pragma unroll
        for (int r = 0; r < 4; ++r) cr[r] = __shfl(corr, (hi << 2) + r);
#pragma unroll
        for (int nf = 0; nf < 8; ++nf)
#pragma unroll
            for (int r = 0; r < 4; ++r) oacc[nf][r] *= cr[r];

        // pack P (bf16) as PV A-operand; k-bijection: slot i of chunk c2
        //   -> k = 32*c2 + hi*4 + (i&3) + 16*(i>>2)
        s16x8 pa[2];
#pragma unroll
        for (int c2 = 0; c2 < 2; ++c2) {
            s16x8 t;
#pragma unroll
            for (int e = 0; e < 4; ++e) t[e] = (short)f2bf(p[2 * c2][e]);
#pragma unroll
            for (int e = 0; e < 4; ++e) t[4 + e] = (short)f2bf(p[2 * c2 + 1][e]);
            pa[c2] = t;
        }
        // PV: B-frag slot i reads Vs[d][same k-bijection]
        __builtin_amdgcn_s_setprio(1);
#pragma unroll
        for (int nf = 0; nf < 8; ++nf) {
            int d = nf * 16 + lo;
            const char* vrow = (const char*)Vs[cur] + d * 128;
            int swz = (d & 7) << 4;
#pragma unroll
            for (int c2 = 0; c2 < 2; ++c2) {
                int ob = (hi << 3) + (c2 << 6);
                s16x4 vlo = *(const s16x4*)(vrow + (ob ^ swz));
                s16x4 vhi = *(const s16x4*)(vrow + ((ob + 32) ^ swz));
                s16x8 vf = {vlo[0], vlo[1], vlo[2], vlo[3], vhi[0], vhi[1], vhi[2], vhi[3]};
                oacc[nf] = __builtin_amdgcn_mfma_f32_16x16x32_bf16(pa[c2], vf, oacc[nf], 0, 0, 0);
            }
        }
        __builtin_amdgcn_s_setprio(0);

        FULL_BARRIER();   // all waves done reading buf[cur] before next stage
    }

    // epilogue: normalize, add self-force, write bf16 T
    float linv[4];
#pragma unroll
    for (int r = 0; r < 4; ++r) linv[r] = 1.0f / __shfl(lrun, (hi << 2) + r);
#pragma unroll
    for (int nf = 0; nf < 8; ++nf) {
        int d = nf * 16 + lo;
#pragma unroll
        for (int r = 0; r < 4; ++r) {
            int q2 = qt * 64 + wave * 16 + (hi << 2) + r;
            size_t idx = ((size_t)(b * 2048 + q2) << 10) + h * 128 + d;
            Tb[idx] = f2bf(oacc[nf][r] * linv[r] + bf2f(Sb[idx]));
        }
    }
}

// ---------------- launch ----------------
extern "C" void kernel_launch(void* const* d_in, const int* in_sizes, int n_in,
                              void* d_out, int out_size, void* d_ws, size_t ws_size,
                              hipStream_t stream) {
    const float* x   = (const float*)d_in[0];
    const float* Wk  = (const float*)d_in[1];
    const float* Wv  = (const float*)d_in[2];
    const float* Wsf = (const float*)d_in[3];
    const float* Wo  = (const float*)d_in[4];
    float* out = (float*)d_out;
    char* ws = (char*)d_ws;
    u16* xb  = (u16*)(ws);                       // 8 MB (reused as Tb after proj)
    u16* wkb = (u16*)(ws + (8u << 20));
    u16* wvb = (u16*)(ws + (10u << 20));
    u16* wsb = (u16*)(ws + (12u << 20));
    u16* wob = (u16*)(ws + (14u << 20));
    u16* Kb  = (u16*)(ws + (16u << 20));         // 8 MB
    u16* Vtb = (u16*)(ws + (24u << 20));         // 8 MB, [BH][128][2048]
    u16* Sbf = (u16*)(ws + (32u << 20));         // 8 MB
    u16* Tb  = xb;                               // alias: xb dead after proj GEMM

    cast_all<<<8192, 256, 0, stream>>>(x, Wk, Wv, Wsf, Wo, xb, wkb, wvb, wsb, wob);
    gemm_nt<0><<<dim3(8, 32, 3), 256, 0, stream>>>(xb, wkb, wvb, wsb, Kb, Vtb, Sbf, nullptr);
    attn_kernel<<<dim3(32, 16), 256, 0, stream>>>(Kb, Vtb, Sbf, Tb);
    gemm_nt<1><<<dim3(8, 32, 1), 256, 0, stream>>>(Tb, wob, nullptr, nullptr,
                                                   nullptr, nullptr, nullptr, out);
}

// Round 3
// 227.659 us; speedup vs baseline: 1.2974x; 1.0672x over previous
//
#include <hip/hip_runtime.h>

// EnergyFunction: B=2, S=2048, D=1024, H=8, hd=128
//   K = x@Wk^T, V = x@Wv^T, Sf = x@Wself^T   (all bf16 intermediates)
//   att = softmax(-(K K^T)/sqrt(128), causal) @ V
//   out = (att + Sf) @ Wout^T                 (fp32 output)
// ws layout (40 MB): xb/Tb 0..8M | Wkb 8M | Wvb 10M | Wsb 12M | Wob 14M
//                    | Kb 16M | Vtb 24M (pre-transposed [BH][128][2048]) | Sbf 32M

typedef unsigned short u16;
typedef short s16x8 __attribute__((ext_vector_type(8)));
typedef short s16x4 __attribute__((ext_vector_type(4)));
typedef unsigned short u16x4 __attribute__((ext_vector_type(4)));
typedef float f32x4 __attribute__((ext_vector_type(4)));

#define DEV __device__ __forceinline__

DEV u16 f2bf(float f) {
    union { float f; unsigned u; } v; v.f = f;
    return (u16)((v.u + 0x7FFFu + ((v.u >> 16) & 1u)) >> 16);
}
DEV float bf2f(u16 h) {
    union { unsigned u; float f; } v; v.u = ((unsigned)h) << 16;
    return v.f;
}
DEV void gload16(const void* g, void* l) {
    __builtin_amdgcn_global_load_lds(
        (const __attribute__((address_space(1))) void*)g,
        (__attribute__((address_space(3))) void*)l, 16, 0, 0);
}

#define FULL_BARRIER()                          \
    do {                                        \
        __builtin_amdgcn_sched_barrier(0);      \
        __builtin_amdgcn_s_barrier();           \
        __builtin_amdgcn_sched_barrier(0);      \
    } while (0)

// ---------------- cast fp32 -> bf16 (x + 4 weights fused) ----------------
__global__ __launch_bounds__(256) void cast_all(
    const float* __restrict__ x, const float* __restrict__ wk,
    const float* __restrict__ wv, const float* __restrict__ wsf,
    const float* __restrict__ wo,
    u16* __restrict__ xb, u16* __restrict__ wkb, u16* __restrict__ wvb,
    u16* __restrict__ wsb, u16* __restrict__ wob) {
    int i = blockIdx.x * 256 + threadIdx.x;            // float4 index
    const int NX = (2 * 2048 * 1024) / 4;              // 1048576
    const int NW = (1024 * 1024) / 4;                  // 262144
    const float* src; u16* dst; int off;
    if (i < NX)              { src = x;   dst = xb;  off = i; }
    else if (i < NX + NW)    { src = wk;  dst = wkb; off = i - NX; }
    else if (i < NX + 2*NW)  { src = wv;  dst = wvb; off = i - NX - NW; }
    else if (i < NX + 3*NW)  { src = wsf; dst = wsb; off = i - NX - 2*NW; }
    else                     { src = wo;  dst = wob; off = i - NX - 3*NW; }
    float4 v = ((const float4*)src)[off];
    u16x4 o = { f2bf(v.x), f2bf(v.y), f2bf(v.z), f2bf(v.w) };
    ((u16x4*)dst)[off] = o;
}

// ---------------- NT GEMM: C[m][n] = sum_k A[m][k]*W[n][k] ----------------
// 128xBN tile, BK=32, 4 waves (2x2), 16x16x32 bf16 MFMA.
// Double-buffered LDS, issue-early/wait-late counted vmcnt (T3/T4 minimum).
// MODE 0 (BN=128): z picks {Wk->Kb, Wv->Vtb (per-head transposed), Wself->Sbf}
// MODE 1 (BN=64): bf16 in -> fp32 out (final projection), 512 blocks = 2/CU
template <int MODE, int BN>
__global__ __launch_bounds__(256) void gemm_nt(
    const u16* __restrict__ A, const u16* __restrict__ W0,
    const u16* __restrict__ W1, const u16* __restrict__ W2,
    u16* __restrict__ O0, u16* __restrict__ O1, u16* __restrict__ O2,
    float* __restrict__ Of) {
    constexpr int NJ = BN / 32;                  // j-fragments per wave
    constexpr int BLOADS = (BN * 64) / 4096;     // per-wave B gloads (2 or 1)
    __shared__ __align__(16) u16 As[2][128 * 32];
    __shared__ __align__(16) u16 Bs[2][BN * 32];
    const int tid = threadIdx.x, lane = tid & 63, wave = tid >> 6;
    const int wr = wave >> 1, wc = wave & 1;
    const int m0 = blockIdx.y * 128, n0 = blockIdx.x * BN;
    const u16* Bw = W0;
    if (MODE == 0) Bw = (blockIdx.z == 0) ? W0 : (blockIdx.z == 1) ? W1 : W2;

    f32x4 acc[4][NJ];
#pragma unroll
    for (int i = 0; i < 4; ++i)
#pragma unroll
        for (int j = 0; j < NJ; ++j) acc[i][j] = f32x4{0.f, 0.f, 0.f, 0.f};

    // staging geometry: A tile [128][32] (64B rows), B tile [BN][32]
    const int o1 = wave * 1024 + lane * 16;
    const int r1 = o1 >> 6, c1 = (o1 & 63) >> 1;
    const int o2 = o1 + 4096;
    const int r2 = o2 >> 6, c2 = (o2 & 63) >> 1;

    auto stage = [&](int k0, int buf) {
        gload16(A + ((size_t)(m0 + r1) << 10) + k0 + c1, (char*)As[buf] + wave * 1024);
        gload16(A + ((size_t)(m0 + r2) << 10) + k0 + c2, (char*)As[buf] + 4096 + wave * 1024);
        gload16(Bw + ((size_t)(n0 + r1) << 10) + k0 + c1, (char*)Bs[buf] + wave * 1024);
        if (BLOADS == 2)
            gload16(Bw + ((size_t)(n0 + r2) << 10) + k0 + c2, (char*)Bs[buf] + 4096 + wave * 1024);
    };

    stage(0, 0);
    for (int t = 0; t < 32; ++t) {
        const int cur = t & 1;
        if (t < 31) {
            stage((t + 1) << 5, cur ^ 1);
            if constexpr (BLOADS == 2)
                asm volatile("s_waitcnt vmcnt(4)" ::: "memory");
            else
                asm volatile("s_waitcnt vmcnt(3)" ::: "memory");
        } else {
            asm volatile("s_waitcnt vmcnt(0)" ::: "memory");
        }
        FULL_BARRIER();
        const int kb = (lane >> 4) << 3;
        s16x8 af[4], bfr[NJ];
#pragma unroll
        for (int i = 0; i < 4; ++i)
            af[i] = *(const s16x8*)&As[cur][(wr * 64 + i * 16 + (lane & 15)) * 32 + kb];
#pragma unroll
        for (int j = 0; j < NJ; ++j)
            bfr[j] = *(const s16x8*)&Bs[cur][(wc * (BN / 2) + j * 16 + (lane & 15)) * 32 + kb];
#pragma unroll
        for (int i = 0; i < 4; ++i)
#pragma unroll
            for (int j = 0; j < NJ; ++j)
                acc[i][j] = __builtin_amdgcn_mfma_f32_16x16x32_bf16(af[i], bfr[j], acc[i][j], 0, 0, 0);
        FULL_BARRIER();
    }

    // epilogue: C/D layout col=lane&15 (n), row=(lane>>4)*4+reg (m)
    const int mb0 = m0 + wr * 64, nb0 = n0 + wc * (BN / 2);
    if (MODE == 1) {
#pragma unroll
        for (int i = 0; i < 4; ++i)
#pragma unroll
            for (int j = 0; j < NJ; ++j) {
                int n = nb0 + j * 16 + (lane & 15);
                int mbase = mb0 + i * 16 + ((lane >> 4) << 2);
#pragma unroll
                for (int r = 0; r < 4; ++r)
                    Of[((size_t)(mbase + r) << 10) + n] = acc[i][j][r];
            }
    } else if (blockIdx.z == 1) {
        // V: write transposed per head: Vt[(b*8+h)*128 + d][s], pack 4 s per store
#pragma unroll
        for (int i = 0; i < 4; ++i)
#pragma unroll
            for (int j = 0; j < NJ; ++j) {
                int n = nb0 + j * 16 + (lane & 15);
                int h = n >> 7, d = n & 127;
                int mbase = mb0 + i * 16 + ((lane >> 4) << 2);
                int b = mbase >> 11, s = mbase & 2047;
                u16x4 pk;
#pragma unroll
                for (int r = 0; r < 4; ++r) pk[r] = f2bf(acc[i][j][r]);
                *(u16x4*)(O1 + (((size_t)(b * 8 + h) << 7) + d) * 2048 + s) = pk;
            }
    } else {
        u16* dst = blockIdx.z ? O2 : O0;
#pragma unroll
        for (int i = 0; i < 4; ++i)
#pragma unroll
            for (int j = 0; j < NJ; ++j) {
                int n = nb0 + j * 16 + (lane & 15);
                int mbase = mb0 + i * 16 + ((lane >> 4) << 2);
#pragma unroll
                for (int r = 0; r < 4; ++r)
                    dst[((size_t)(mbase + r) << 10) + n] = f2bf(acc[i][j][r]);
            }
    }
}

// ---------------- causal flash attention over keys ----------------
// grid (32 qtiles, 16 bh), 256 thr. Wave w owns q rows qt*64+w*16..+15.
// qt remap anti-correlates co-resident blocks (id and id+256 share bx and
// land on the same CU; bh and bh+8 pair -> qt sums to 31 -> balanced).
// Double-buffered K/V staged via global_load_lds with pre-swizzled source;
// counted vmcnt(8) keeps next tile's loads in flight under compute.
__global__ __launch_bounds__(256) void attn_kernel(
    const u16* __restrict__ Kb, const u16* __restrict__ Vtb,
    const u16* __restrict__ Sb, u16* __restrict__ Tb) {
    __shared__ __align__(16) u16 Ks[2][64 * 128];   // K tile [k][dhead], swizzled
    __shared__ __align__(16) u16 Vs[2][128 * 64];   // V^T tile [dhead][k], swizzled
    const int tid = threadIdx.x, lane = tid & 63, wave = tid >> 6;
    const int qt = (blockIdx.y & 8) ? blockIdx.x : (31 - blockIdx.x);
    const int bh = blockIdx.y, b = bh >> 3, h = bh & 7;
    const int hi = lane >> 4, lo = lane & 15;
    const int qlocal = wave * 16 + lo;
    const int qrow = qt * 64 + qlocal;

    s16x8 qf[4];
    {
        const u16* qp = Kb + ((size_t)(b * 2048 + qrow) << 10) + h * 128 + (hi << 3);
#pragma unroll
        for (int c = 0; c < 4; ++c) qf[c] = *(const s16x8*)(qp + c * 32);
    }

    // pre-swizzled staging source bases (per-lane), linear LDS dests (per-wave)
    const u16* ksrcb[4];
    const u16* vsrcb[4];
    int ldst[4];
#pragma unroll
    for (int j = 0; j < 4; ++j) {
        int p = wave * 4096 + j * 1024 + lane * 16;   // linear byte pos in 16KB tile
        ldst[j] = wave * 4096 + j * 1024;             // wave-uniform LDS dest
        int rk = p >> 8, cbs = (p & 255) ^ ((rk & 7) << 4);
        ksrcb[j] = Kb + ((size_t)(b * 2048 + rk) << 10) + h * 128 + (cbs >> 1);
        int dv = p >> 7, kbs = (p & 127) ^ ((dv & 7) << 4);
        vsrcb[j] = Vtb + (((size_t)(bh * 128 + dv)) << 11) + (kbs >> 1);
    }

    auto stage = [&](int ks0, int buf) {
        char* kb = (char*)Ks[buf];
        char* vb = (char*)Vs[buf];
#pragma unroll
        for (int j = 0; j < 4; ++j) {
            gload16(ksrcb[j] + ((size_t)ks0 << 10), kb + ldst[j]);
            gload16(vsrcb[j] + ks0, vb + ldst[j]);
        }
    };

    f32x4 oacc[8];
#pragma unroll
    for (int nf = 0; nf < 8; ++nf) oacc[nf] = f32x4{0.f, 0.f, 0.f, 0.f};
    float mrun = -__builtin_inff(), lrun = 0.f;
    const float SC = -0.12751741566723328f;  // -log2(e)/sqrt(128)

    stage(0, 0);
    asm volatile("s_waitcnt vmcnt(0)" ::: "memory");
    FULL_BARRIER();

    for (int kt = 0; kt <= qt; ++kt) {
        const int cur = kt & 1;
        if (kt < qt) {
            stage((kt + 1) << 6, cur ^ 1);            // 8 loads in flight
            asm volatile("s_waitcnt vmcnt(8)" ::: "memory");
        } else {
            asm volatile("s_waitcnt vmcnt(0)" ::: "memory");
        }
        FULL_BARRIER();                               // tile kt landed for all waves

        // QK^T (swapped): sf[mf] reg r = score[k = ks0+mf*16+hi*4+r][q]
        f32x4 sf[4];
        __builtin_amdgcn_s_setprio(1);
#pragma unroll
        for (int mf = 0; mf < 4; ++mf) {
            f32x4 s = {0.f, 0.f, 0.f, 0.f};
            int kr = mf * 16 + lo;
            const char* rowp = (const char*)Ks[cur] + kr * 256;
            int swz = (kr & 7) << 4;
#pragma unroll
            for (int c = 0; c < 4; ++c) {
                s16x8 kf = *(const s16x8*)(rowp + ((c * 64 + hi * 16) ^ swz));
                s = __builtin_amdgcn_mfma_f32_16x16x32_bf16(kf, qf[c], s, 0, 0, 0);
            }
            sf[mf] = s;
        }
        __builtin_amdgcn_s_setprio(0);

        const bool diag = (kt == qt);
        float p[4][4];
        float pm = -__builtin_inff();
#pragma unroll
        for (int mf = 0; mf < 4; ++mf)
#pragma unroll
            for (int r = 0; r < 4; ++r) {
                float sv = sf[mf][r] * SC;
                if (diag) {
                    int klocal = mf * 16 + (hi << 2) + r;
                    if (klocal > qlocal) sv = -__builtin_inff();
                }
                p[mf][r] = sv;
                pm = fmaxf(pm, sv);
            }
        pm = fmaxf(pm, __shfl_xor(pm, 16));
        pm = fmaxf(pm, __shfl_xor(pm, 32));

        // T13 defer-rescale: skip the O-rescale when max didn't grow
        const bool grow = !__all(pm <= mrun);
        float mnew = grow ? fmaxf(mrun, pm) : mrun;
        if (grow) {
            float corr = exp2f(mrun - mnew);          // first tile: exp2(-inf)=0
            lrun *= corr;
            float cr[4];
#pragma unroll
            for (int r = 0; r < 4; ++r) cr[r] = __shfl(corr, (hi << 2) + r);
#pragma unroll
            for (int nf = 0; nf < 8; ++nf)
#pragma unroll
                for (int r = 0; r < 4; ++r) oacc[nf][r] *= cr[r];
            mrun = mnew;
        }

        float psum = 0.f;
        float p2[4][4];
#pragma unroll
        for (int mf = 0; mf < 4; ++mf)
#pragma unroll
            for (int r = 0; r < 4; ++r) {
                float e = exp2f(p[mf][r] - mnew);
                p2[mf][r] = e;
                psum += e;
            }
        psum += __shfl_xor(psum, 16);
        psum += __shfl_xor(psum, 32);
        lrun += psum;

        // pack P (bf16) as PV A-operand; k-bijection: slot i of chunk c2
        //   -> k = 32*c2 + hi*4 + (i&3) + 16*(i>>2)
        s16x8 pa[2];
#pragma unroll
        for (int c2 = 0; c2 < 2; ++c2) {
            s16x8 t;
#pragma unroll
            for (int e = 0; e < 4; ++e) t[e] = (short)f2bf(p2[2 * c2][e]);
#pragma unroll
            for (int e = 0; e < 4; ++e) t[4 + e] = (short)f2bf(p2[2 * c2 + 1][e]);
            pa[c2] = t;
        }
        // PV: B-frag slot i reads Vs[d][same k-bijection]
        __builtin_amdgcn_s_setprio(1);
#pragma unroll
        for (int nf = 0; nf < 8; ++nf) {
            int d = nf * 16 + lo;
            const char* vrow = (const char*)Vs[cur] + d * 128;
            int swz = (d & 7) << 4;
#pragma unroll
            for (int c2 = 0; c2 < 2; ++c2) {
                int ob = (hi << 3) + (c2 << 6);
                s16x4 vlo = *(const s16x4*)(vrow + (ob ^ swz));
                s16x4 vhi = *(const s16x4*)(vrow + ((ob + 32) ^ swz));
                s16x8 vf = {vlo[0], vlo[1], vlo[2], vlo[3], vhi[0], vhi[1], vhi[2], vhi[3]};
                oacc[nf] = __builtin_amdgcn_mfma_f32_16x16x32_bf16(pa[c2], vf, oacc[nf], 0, 0, 0);
            }
        }
        __builtin_amdgcn_s_setprio(0);

        FULL_BARRIER();   // all waves done reading buf[cur] before next stage
    }

    // epilogue: normalize, add self-force, write bf16 T
    float linv[4];
#pragma unroll
    for (int r = 0; r < 4; ++r) linv[r] = 1.0f / __shfl(lrun, (hi << 2) + r);
#pragma unroll
    for (int nf = 0; nf < 8; ++nf) {
        int d = nf * 16 + lo;
#pragma unroll
        for (int r = 0; r < 4; ++r) {
            int q2 = qt * 64 + wave * 16 + (hi << 2) + r;
            size_t idx = ((size_t)(b * 2048 + q2) << 10) + h * 128 + d;
            Tb[idx] = f2bf(oacc[nf][r] * linv[r] + bf2f(Sb[idx]));
        }
    }
}

// ---------------- launch ----------------
extern "C" void kernel_launch(void* const* d_in, const int* in_sizes, int n_in,
                              void* d_out, int out_size, void* d_ws, size_t ws_size,
                              hipStream_t stream) {
    const float* x   = (const float*)d_in[0];
    const float* Wk  = (const float*)d_in[1];
    const float* Wv  = (const float*)d_in[2];
    const float* Wsf = (const float*)d_in[3];
    const float* Wo  = (const float*)d_in[4];
    float* out = (float*)d_out;
    char* ws = (char*)d_ws;
    u16* xb  = (u16*)(ws);                       // 8 MB (reused as Tb after proj)
    u16* wkb = (u16*)(ws + (8u << 20));
    u16* wvb = (u16*)(ws + (10u << 20));
    u16* wsb = (u16*)(ws + (12u << 20));
    u16* wob = (u16*)(ws + (14u << 20));
    u16* Kb  = (u16*)(ws + (16u << 20));         // 8 MB
    u16* Vtb = (u16*)(ws + (24u << 20));         // 8 MB, [BH][128][2048]
    u16* Sbf = (u16*)(ws + (32u << 20));         // 8 MB
    u16* Tb  = xb;                               // alias: xb dead after proj GEMM

    cast_all<<<8192, 256, 0, stream>>>(x, Wk, Wv, Wsf, Wo, xb, wkb, wvb, wsb, wob);
    gemm_nt<0, 128><<<dim3(8, 32, 3), 256, 0, stream>>>(xb, wkb, wvb, wsb, Kb, Vtb, Sbf, nullptr);
    attn_kernel<<<dim3(32, 16), 256, 0, stream>>>(Kb, Vtb, Sbf, Tb);
    gemm_nt<1, 64><<<dim3(16, 32, 1), 256, 0, stream>>>(Tb, wob, nullptr, nullptr,
                                                        nullptr, nullptr, nullptr, out);
}